// Round 1
// baseline (2724.257 us; speedup 1.0000x reference)
//
#include <hip/hip_runtime.h>
#include <math.h>

#ifndef M_PI
#define M_PI 3.14159265358979323846
#endif

#define LEN   4096
#define NB    32
#define NH    64
#define NF    2048   // max modes kept (< 2049 bins)
#define NLAYER 4

// ---------------------------------------------------------------------------
// twiddle table: tw[k] = exp(-2*pi*i*k/4096), k = 0..2047
__global__ __launch_bounds__(256) void fill_tw(float2* __restrict__ tw) {
    int k = blockIdx.x * 256 + threadIdx.x;
    if (k < 2048) {
        double ang = -2.0 * M_PI * (double)k / 4096.0;
        tw[k] = make_float2((float)cos(ang), (float)sin(ang));
    }
}

// ---------------------------------------------------------------------------
// encoder: v[b,h,l] = eb[h] + ew[h,0]*x + ew[h,1]*u0 + ew[h,2]*u1 + ew[h,3]*u2
__global__ __launch_bounds__(256) void encoder_k(
        const float* __restrict__ x, const float* __restrict__ u,
        const float* __restrict__ ew, const float* __restrict__ eb,
        float* __restrict__ v) {
    int tid = blockIdx.x * 256 + threadIdx.x;   // 0 .. NB*LEN-1
    int b = tid >> 12;
    int l = tid & (LEN - 1);
    float xv = x[(size_t)b * LEN + l];
    float u0 = u[((size_t)b * 3 + 0) * LEN + l];
    float u1 = u[((size_t)b * 3 + 1) * LEN + l];
    float u2 = u[((size_t)b * 3 + 2) * LEN + l];
    for (int h = 0; h < NH; ++h) {
        float a = eb[h] + ew[h*4+0]*xv + ew[h*4+1]*u0 + ew[h*4+2]*u1 + ew[h*4+3]*u2;
        v[((size_t)b * NH + h) * LEN + l] = a;
    }
}

// ---------------------------------------------------------------------------
// forward FFT: one block per row (b*64+i). Complex radix-2 DIT, 4096 points,
// real input, writes bins 0..2047 to Xt[row][f].
__global__ __launch_bounds__(256) void fft_fwd_k(
        const float* __restrict__ vin, float2* __restrict__ Xt,
        const float2* __restrict__ tw) {
    __shared__ float2 a[4096];
    int row = blockIdx.x;
    const float* src = vin + (size_t)row * LEN;
    int t = threadIdx.x;
    for (int j = 0; j < 16; ++j) {
        int idx = t + j * 256;
        int r = __brev((unsigned)idx) >> 20;
        a[r] = make_float2(src[idx], 0.0f);
    }
    __syncthreads();
    for (int s = 1; s <= 12; ++s) {
        int half = 1 << (s - 1);
        int tws  = 12 - s;
        for (int j = t; j < 2048; j += 256) {
            int k = j & (half - 1);
            int base = ((j >> (s - 1)) << s) + k;
            float2 w  = tw[k << tws];
            float2 x0 = a[base];
            float2 x1 = a[base + half];
            float tr = w.x * x1.x - w.y * x1.y;
            float ti = w.x * x1.y + w.y * x1.x;
            a[base]        = make_float2(x0.x + tr, x0.y + ti);
            a[base + half] = make_float2(x0.x - tr, x0.y - ti);
        }
        __syncthreads();
    }
    float2* dst = Xt + (size_t)row * NF;
    for (int j = 0; j < 8; ++j) {
        int f = t + j * 256;
        dst[f] = a[f];
    }
}

// ---------------------------------------------------------------------------
// inverse FFT + bias: one block per row (b*64+o). Builds Hermitian spectrum
// from 2048 stored bins (Nyquist = 0), inverse radix-2, writes real part/4096
// + (sb0+sb1+sb2)[layer][o].
__global__ __launch_bounds__(256) void fft_inv_k(
        const float2* __restrict__ Yt, float* __restrict__ sout,
        const float2* __restrict__ tw,
        const float* __restrict__ sb0, const float* __restrict__ sb1,
        const float* __restrict__ sb2, int layer) {
    __shared__ float2 a[4096];
    int row = blockIdx.x;
    int o = row & (NH - 1);
    const float2* src = Yt + (size_t)row * NF;
    int t = threadIdx.x;
    for (int j = 0; j < 8; ++j) {
        int f = t + j * 256;                    // 0..2047
        float2 yv = src[f];
        a[__brev((unsigned)f) >> 20] = yv;
    }
    for (int j = 0; j < 8; ++j) {
        int f = 2048 + t + j * 256;             // 2048..4095
        float2 val;
        if (f == 2048) {
            val = make_float2(0.0f, 0.0f);
        } else {
            float2 yv = src[4096 - f];
            val = make_float2(yv.x, -yv.y);
        }
        a[__brev((unsigned)f) >> 20] = val;
    }
    __syncthreads();
    for (int s = 1; s <= 12; ++s) {
        int half = 1 << (s - 1);
        int tws  = 12 - s;
        for (int j = t; j < 2048; j += 256) {
            int k = j & (half - 1);
            int base = ((j >> (s - 1)) << s) + k;
            float2 w = tw[k << tws];
            w.y = -w.y;                          // conjugate: inverse transform
            float2 x0 = a[base];
            float2 x1 = a[base + half];
            float tr = w.x * x1.x - w.y * x1.y;
            float ti = w.x * x1.y + w.y * x1.x;
            a[base]        = make_float2(x0.x + tr, x0.y + ti);
            a[base + half] = make_float2(x0.x - tr, x0.y - ti);
        }
        __syncthreads();
    }
    float bias = sb0[layer * NH + o] + sb1[layer * NH + o] + sb2[layer * NH + o];
    float* dst = sout + (size_t)row * LEN;
    const float scale = 1.0f / 4096.0f;
    for (int j = 0; j < 16; ++j) {
        int l = t + j * 256;
        dst[l] = a[l].x * scale + bias;
    }
}

// ---------------------------------------------------------------------------
// 2048x2048 complex transpose, 32x32 tiles
__global__ __launch_bounds__(256) void transpose_k(
        const float2* __restrict__ src, float2* __restrict__ dst) {
    __shared__ float2 tile[32][33];
    int tx = threadIdx.x & 31;
    int ty = threadIdx.x >> 5;                   // 0..7
    int col = blockIdx.x * 32 + tx;
    for (int j = 0; j < 32; j += 8) {
        int row = blockIdx.y * 32 + ty + j;
        tile[ty + j][tx] = src[(size_t)row * 2048 + col];
    }
    __syncthreads();
    int ocol = blockIdx.y * 32 + tx;
    for (int j = 0; j < 32; j += 8) {
        int orow = blockIdx.x * 32 + ty + j;
        dst[(size_t)orow * 2048 + ocol] = tile[tx][ty + j];
    }
}

// ---------------------------------------------------------------------------
// spectral matmul: Y[f,b,o] = sum_k [f<M_k] sum_i X[f,b,i] * Wk[layer,i,o,f]
// grid: (NF/8, 2). block 256. Each block: 8 consecutive f, all 32 b, one
// 32-wide o-half. Thread owns (4 b) x (8 o) for one f.
__global__ __launch_bounds__(256) void specmm_k(
        const float2* __restrict__ X, float2* __restrict__ Y,
        const float* __restrict__ w0, const float* __restrict__ w1,
        const float* __restrict__ w2, int layer) {
    __shared__ float2 Xs[8][32][9];   // [i][b][f] (+1 pad)
    __shared__ float2 Ws[8][32][9];   // [i][o][f] (+1 pad)
    int f0 = blockIdx.x * 8;
    int oh = blockIdx.y;              // o-half: 0 or 1
    int t  = threadIdx.x;
    int ff = t & 7;
    int u  = t >> 3;                  // 0..31
    int b0  = (u & 7) * 4;            // 4 batches
    int oo0 = (u >> 3) * 8;           // 8 outputs (within half)
    float2 acc[4][8];
    for (int bb = 0; bb < 4; ++bb)
        for (int oo = 0; oo < 8; ++oo)
            acc[bb][oo] = make_float2(0.0f, 0.0f);

    const float* wptr[3] = { w0, w1, w2 };
    const int    Mk[3]   = { 512, 1024, 2048 };

    #pragma unroll
    for (int k = 0; k < 3; ++k) {
        if (f0 >= Mk[k]) continue;
        const int M = Mk[k];
        const float2* wbase = (const float2*)wptr[k] + (size_t)layer * NH * NH * M;
        for (int ic = 0; ic < 8; ++ic) {
            __syncthreads();
            {   // stage X chunk: Xs[ii][b][f]
                int bq = t & 31, fq = t >> 5;
                const float2* gp = X + ((size_t)(f0 + fq) * (NB * NH) + bq * NH + ic * 8);
                #pragma unroll
                for (int ii = 0; ii < 8; ++ii) Xs[ii][bq][fq] = gp[ii];
            }
            {   // stage W chunk: Ws[ii][o][f], coalesced 64B runs along f
                int oq = t & 31, iq = t >> 5;
                const float2* gp = wbase + ((size_t)(ic * 8 + iq) * NH + (oh * 32 + oq)) * M + f0;
                #pragma unroll
                for (int ii = 0; ii < 8; ++ii) Ws[iq][oq][ii] = gp[ii];
            }
            __syncthreads();
            #pragma unroll
            for (int ii = 0; ii < 8; ++ii) {
                float2 xr[4], wr[8];
                #pragma unroll
                for (int bb = 0; bb < 4; ++bb) xr[bb] = Xs[ii][b0 + bb][ff];
                #pragma unroll
                for (int oo = 0; oo < 8; ++oo) wr[oo] = Ws[ii][oo0 + oo][ff];
                #pragma unroll
                for (int bb = 0; bb < 4; ++bb)
                    #pragma unroll
                    for (int oo = 0; oo < 8; ++oo) {
                        acc[bb][oo].x += xr[bb].x * wr[oo].x - xr[bb].y * wr[oo].y;
                        acc[bb][oo].y += xr[bb].x * wr[oo].y + xr[bb].y * wr[oo].x;
                    }
            }
        }
    }
    for (int bb = 0; bb < 4; ++bb) {
        float2* yp = Y + ((size_t)(f0 + ff) * (NB * NH) + (b0 + bb) * NH + oh * 32 + oo0);
        #pragma unroll
        for (int oo = 0; oo < 8; ++oo) yp[oo] = acc[bb][oo];
    }
}

// ---------------------------------------------------------------------------
// conv1 + gelu(tanh approx): h[b,o,l] = gelu(cb[o] + sum_i cw[o,i]*s[b,i,l])
__global__ __launch_bounds__(256) void conv_gelu_k(
        const float* __restrict__ s, const float* __restrict__ cw,
        const float* __restrict__ cb, int layer, float* __restrict__ h) {
    int tid = blockIdx.x * 256 + threadIdx.x;
    int b = tid >> 12;
    int l = tid & (LEN - 1);
    float xr[NH];
    #pragma unroll
    for (int i = 0; i < NH; ++i) xr[i] = s[((size_t)b * NH + i) * LEN + l];
    const float* w  = cw + (size_t)layer * NH * NH;
    const float* bb = cb + layer * NH;
    for (int o = 0; o < NH; ++o) {
        float acc = bb[o];
        #pragma unroll
        for (int i = 0; i < NH; ++i) acc += w[o * NH + i] * xr[i];
        float c = 0.7978845608028654f * (acc + 0.044715f * acc * acc * acc);
        float g = 0.5f * acc * (1.0f + tanhf(c));
        h[((size_t)b * NH + o) * LEN + l] = g;
    }
}

// ---------------------------------------------------------------------------
// conv2 + residual: v[b,o,l] += cb[o] + sum_i cw[o,i]*h[b,i,l]
__global__ __launch_bounds__(256) void conv_res_k(
        const float* __restrict__ h, const float* __restrict__ cw,
        const float* __restrict__ cb, int layer, float* __restrict__ v) {
    int tid = blockIdx.x * 256 + threadIdx.x;
    int b = tid >> 12;
    int l = tid & (LEN - 1);
    float xr[NH];
    #pragma unroll
    for (int i = 0; i < NH; ++i) xr[i] = h[((size_t)b * NH + i) * LEN + l];
    const float* w  = cw + (size_t)layer * NH * NH;
    const float* bb = cb + layer * NH;
    for (int o = 0; o < NH; ++o) {
        float acc = bb[o];
        #pragma unroll
        for (int i = 0; i < NH; ++i) acc += w[o * NH + i] * xr[i];
        size_t idx = ((size_t)b * NH + o) * LEN + l;
        v[idx] = v[idx] + acc;
    }
}

// ---------------------------------------------------------------------------
// decoder: out[b,l] = db + sum_i dw[i]*v[b,i,l]
__global__ __launch_bounds__(256) void decoder_k(
        const float* __restrict__ v, const float* __restrict__ dw,
        const float* __restrict__ db, float* __restrict__ out) {
    int tid = blockIdx.x * 256 + threadIdx.x;
    int b = tid >> 12;
    int l = tid & (LEN - 1);
    float acc = db[0];
    for (int i = 0; i < NH; ++i) acc += dw[i] * v[((size_t)b * NH + i) * LEN + l];
    out[(size_t)b * LEN + l] = acc;
}

// ---------------------------------------------------------------------------
extern "C" void kernel_launch(void* const* d_in, const int* in_sizes, int n_in,
                              void* d_out, int out_size, void* d_ws, size_t ws_size,
                              hipStream_t stream) {
    const float* u_in   = (const float*)d_in[0];
    const float* x_in   = (const float*)d_in[1];
    const float* enc_w  = (const float*)d_in[2];
    const float* enc_b  = (const float*)d_in[3];
    const float* dec_w  = (const float*)d_in[4];
    const float* dec_b  = (const float*)d_in[5];
    const float* conv1w = (const float*)d_in[6];
    const float* conv1b = (const float*)d_in[7];
    const float* conv2w = (const float*)d_in[8];
    const float* conv2b = (const float*)d_in[9];
    const float* sw0    = (const float*)d_in[10];
    const float* sb0    = (const float*)d_in[11];
    const float* sw1    = (const float*)d_in[12];
    const float* sb1    = (const float*)d_in[13];
    const float* sw2    = (const float*)d_in[14];
    const float* sb2    = (const float*)d_in[15];

    // workspace carve-up
    const size_t CPLX = (size_t)2048 * 2048;          // elements per complex buffer
    const size_t REAL = (size_t)NB * NH * LEN;        // elements per real buffer
    char* base = (char*)d_ws;
    float2* tw   = (float2*)base;                                  // 16 KB
    float2* bufA = (float2*)(base + 16384);                        // 32 MB
    float2* bufB = bufA + CPLX;                                    // 32 MB
    float*  sbuf = (float*)(bufB + CPLX);                          // 32 MB
    float*  vbuf = sbuf + REAL;                                    // 32 MB
    size_t need = 16384 + 2 * CPLX * sizeof(float2) + 2 * REAL * sizeof(float);
    if (ws_size < need) return;  // insufficient scratch: leave d_out poisoned (visible failure)

    fill_tw<<<8, 256, 0, stream>>>(tw);
    encoder_k<<<(NB * LEN) / 256, 256, 0, stream>>>(x_in, u_in, enc_w, enc_b, vbuf);

    for (int l = 0; l < NLAYER; ++l) {
        fft_fwd_k  <<<NB * NH, 256, 0, stream>>>(vbuf, bufA, tw);
        transpose_k<<<dim3(64, 64), 256, 0, stream>>>(bufA, bufB);          // Xt -> X (f-major)
        specmm_k   <<<dim3(NF / 8, 2), 256, 0, stream>>>(bufB, bufA, sw0, sw1, sw2, l);
        transpose_k<<<dim3(64, 64), 256, 0, stream>>>(bufA, bufB);          // Y -> Yt (row-major)
        fft_inv_k  <<<NB * NH, 256, 0, stream>>>(bufB, sbuf, tw, sb0, sb1, sb2, l);
        conv_gelu_k<<<(NB * LEN) / 256, 256, 0, stream>>>(sbuf, conv1w, conv1b, l, (float*)bufA);
        conv_res_k <<<(NB * LEN) / 256, 256, 0, stream>>>((float*)bufA, conv2w, conv2b, l, vbuf);
    }
    decoder_k<<<(NB * LEN) / 256, 256, 0, stream>>>(vbuf, dec_w, dec_b, (float*)d_out);
}

// Round 2
// 1847.977 us; speedup vs baseline: 1.4742x; 1.4742x over previous
//
#include <hip/hip_runtime.h>
#include <math.h>

#ifndef M_PI
#define M_PI 3.14159265358979323846
#endif

#define LEN   4096
#define NB    32
#define NH    64
#define NF    2048   // max modes kept (< 2049 bins)
#define NLAYER 4

// ---------------------------------------------------------------------------
// twiddle table: tw[k] = exp(-2*pi*i*k/4096), k = 0..2047
__global__ __launch_bounds__(256) void fill_tw(float2* __restrict__ tw) {
    int k = blockIdx.x * 256 + threadIdx.x;
    if (k < 2048) {
        double ang = -2.0 * M_PI * (double)k / 4096.0;
        tw[k] = make_float2((float)cos(ang), (float)sin(ang));
    }
}

// ---------------------------------------------------------------------------
// encoder: v[b,h,l] = eb[h] + ew[h,0]*x + ew[h,1]*u0 + ew[h,2]*u1 + ew[h,3]*u2
__global__ __launch_bounds__(256) void encoder_k(
        const float* __restrict__ x, const float* __restrict__ u,
        const float* __restrict__ ew, const float* __restrict__ eb,
        float* __restrict__ v) {
    int tid = blockIdx.x * 256 + threadIdx.x;   // 0 .. NB*LEN-1
    int b = tid >> 12;
    int l = tid & (LEN - 1);
    float xv = x[(size_t)b * LEN + l];
    float u0 = u[((size_t)b * 3 + 0) * LEN + l];
    float u1 = u[((size_t)b * 3 + 1) * LEN + l];
    float u2 = u[((size_t)b * 3 + 2) * LEN + l];
    for (int h = 0; h < NH; ++h) {
        float a = eb[h] + ew[h*4+0]*xv + ew[h*4+1]*u0 + ew[h*4+2]*u1 + ew[h*4+3]*u2;
        v[((size_t)b * NH + h) * LEN + l] = a;
    }
}

// ---------------------------------------------------------------------------
// forward FFT: one block per row (b*64+i). Complex radix-2 DIT, 4096 points,
// real input, writes bins 0..2047 to Xt[row][f].
__global__ __launch_bounds__(256) void fft_fwd_k(
        const float* __restrict__ vin, float2* __restrict__ Xt,
        const float2* __restrict__ tw) {
    __shared__ float2 a[4096];
    int row = blockIdx.x;
    const float* src = vin + (size_t)row * LEN;
    int t = threadIdx.x;
    for (int j = 0; j < 16; ++j) {
        int idx = t + j * 256;
        int r = __brev((unsigned)idx) >> 20;
        a[r] = make_float2(src[idx], 0.0f);
    }
    __syncthreads();
    for (int s = 1; s <= 12; ++s) {
        int half = 1 << (s - 1);
        int tws  = 12 - s;
        for (int j = t; j < 2048; j += 256) {
            int k = j & (half - 1);
            int base = ((j >> (s - 1)) << s) + k;
            float2 w  = tw[k << tws];
            float2 x0 = a[base];
            float2 x1 = a[base + half];
            float tr = w.x * x1.x - w.y * x1.y;
            float ti = w.x * x1.y + w.y * x1.x;
            a[base]        = make_float2(x0.x + tr, x0.y + ti);
            a[base + half] = make_float2(x0.x - tr, x0.y - ti);
        }
        __syncthreads();
    }
    float2* dst = Xt + (size_t)row * NF;
    for (int j = 0; j < 8; ++j) {
        int f = t + j * 256;
        dst[f] = a[f];
    }
}

// ---------------------------------------------------------------------------
// inverse FFT + bias: one block per row (b*64+o). Builds Hermitian spectrum
// from 2048 stored bins (Nyquist = 0), inverse radix-2, writes real part/4096
// + (sb0+sb1+sb2)[layer][o].
__global__ __launch_bounds__(256) void fft_inv_k(
        const float2* __restrict__ Yt, float* __restrict__ sout,
        const float2* __restrict__ tw,
        const float* __restrict__ sb0, const float* __restrict__ sb1,
        const float* __restrict__ sb2, int layer) {
    __shared__ float2 a[4096];
    int row = blockIdx.x;
    int o = row & (NH - 1);
    const float2* src = Yt + (size_t)row * NF;
    int t = threadIdx.x;
    for (int j = 0; j < 8; ++j) {
        int f = t + j * 256;                    // 0..2047
        float2 yv = src[f];
        a[__brev((unsigned)f) >> 20] = yv;
    }
    for (int j = 0; j < 8; ++j) {
        int f = 2048 + t + j * 256;             // 2048..4095
        float2 val;
        if (f == 2048) {
            val = make_float2(0.0f, 0.0f);
        } else {
            float2 yv = src[4096 - f];
            val = make_float2(yv.x, -yv.y);
        }
        a[__brev((unsigned)f) >> 20] = val;
    }
    __syncthreads();
    for (int s = 1; s <= 12; ++s) {
        int half = 1 << (s - 1);
        int tws  = 12 - s;
        for (int j = t; j < 2048; j += 256) {
            int k = j & (half - 1);
            int base = ((j >> (s - 1)) << s) + k;
            float2 w = tw[k << tws];
            w.y = -w.y;                          // conjugate: inverse transform
            float2 x0 = a[base];
            float2 x1 = a[base + half];
            float tr = w.x * x1.x - w.y * x1.y;
            float ti = w.x * x1.y + w.y * x1.x;
            a[base]        = make_float2(x0.x + tr, x0.y + ti);
            a[base + half] = make_float2(x0.x - tr, x0.y - ti);
        }
        __syncthreads();
    }
    float bias = sb0[layer * NH + o] + sb1[layer * NH + o] + sb2[layer * NH + o];
    float* dst = sout + (size_t)row * LEN;
    const float scale = 1.0f / 4096.0f;
    for (int j = 0; j < 16; ++j) {
        int l = t + j * 256;
        dst[l] = a[l].x * scale + bias;
    }
}

// ---------------------------------------------------------------------------
// 2048x2048 complex transpose, 32x32 tiles
__global__ __launch_bounds__(256) void transpose_k(
        const float2* __restrict__ src, float2* __restrict__ dst) {
    __shared__ float2 tile[32][33];
    int tx = threadIdx.x & 31;
    int ty = threadIdx.x >> 5;                   // 0..7
    int col = blockIdx.x * 32 + tx;
    for (int j = 0; j < 32; j += 8) {
        int row = blockIdx.y * 32 + ty + j;
        tile[ty + j][tx] = src[(size_t)row * 2048 + col];
    }
    __syncthreads();
    int ocol = blockIdx.y * 32 + tx;
    for (int j = 0; j < 32; j += 8) {
        int orow = blockIdx.x * 32 + ty + j;
        dst[(size_t)orow * 2048 + ocol] = tile[tx][ty + j];
    }
}

// ---------------------------------------------------------------------------
// spectral matmul with branch-summed weights:
//   Weff[i,o,f] = w2[f] + [f<1024]*w1[f] + [f<512]*w0[f]
//   Y[f,b,o] = sum_i X[f,b,i] * Weff[i,o,f]
// grid: (NF/8, 2). block 256. Each block: 8 consecutive f, all 32 b, one
// 32-wide o-half. Thread owns (4 b) x (8 o) for one f.
__global__ __launch_bounds__(256) void specmm_k(
        const float2* __restrict__ X, float2* __restrict__ Y,
        const float* __restrict__ w0, const float* __restrict__ w1,
        const float* __restrict__ w2, int layer) {
    __shared__ float2 Xs[8][32][9];   // [i][b][f] (+1 pad)
    __shared__ float2 Ws[8][32][9];   // [i][o][f] (+1 pad)
    int f0 = blockIdx.x * 8;
    int oh = blockIdx.y;              // o-half: 0 or 1
    int t  = threadIdx.x;
    int ff = t & 7;
    int u  = t >> 3;                  // 0..31
    int b0  = (u & 7) * 4;            // 4 batches
    int oo0 = (u >> 3) * 8;           // 8 outputs (within half)
    float2 acc[4][8];
    for (int bb = 0; bb < 4; ++bb)
        for (int oo = 0; oo < 8; ++oo)
            acc[bb][oo] = make_float2(0.0f, 0.0f);

    const float2* w0b = (const float2*)w0 + (size_t)layer * NH * NH * 512;
    const float2* w1b = (const float2*)w1 + (size_t)layer * NH * NH * 1024;
    const float2* w2b = (const float2*)w2 + (size_t)layer * NH * NH * 2048;
    const bool has0 = (f0 < 512);
    const bool has1 = (f0 < 1024);

    // staging thread roles (fixed across ic)
    const int bq = t & 31, fq = t >> 5;          // X staging
    const int oq = t & 31, iq = t >> 5;          // W staging

    for (int ic = 0; ic < 8; ++ic) {
        __syncthreads();                          // protect previous iter's reads
        {   // stage X chunk: Xs[ii][b][f]
            const float2* gp = X + ((size_t)(f0 + fq) * (NB * NH) + bq * NH + ic * 8);
            #pragma unroll
            for (int ii = 0; ii < 8; ++ii) Xs[ii][bq][fq] = gp[ii];
        }
        {   // stage W chunk (summed over active branches): Ws[ii][o][f]
            const size_t io = (size_t)(ic * 8 + iq) * NH + (oh * 32 + oq);
            const float2* g2 = w2b + io * 2048 + f0;
            float2 wv[8];
            #pragma unroll
            for (int ii = 0; ii < 8; ++ii) wv[ii] = g2[ii];
            if (has1) {
                const float2* g1 = w1b + io * 1024 + f0;
                #pragma unroll
                for (int ii = 0; ii < 8; ++ii) { float2 v = g1[ii]; wv[ii].x += v.x; wv[ii].y += v.y; }
            }
            if (has0) {
                const float2* g0 = w0b + io * 512 + f0;
                #pragma unroll
                for (int ii = 0; ii < 8; ++ii) { float2 v = g0[ii]; wv[ii].x += v.x; wv[ii].y += v.y; }
            }
            #pragma unroll
            for (int ii = 0; ii < 8; ++ii) Ws[iq][oq][ii] = wv[ii];
        }
        __syncthreads();
        #pragma unroll
        for (int ii = 0; ii < 8; ++ii) {
            float2 xr[4], wr[8];
            #pragma unroll
            for (int bb = 0; bb < 4; ++bb) xr[bb] = Xs[ii][b0 + bb][ff];
            #pragma unroll
            for (int oo = 0; oo < 8; ++oo) wr[oo] = Ws[ii][oo0 + oo][ff];
            #pragma unroll
            for (int bb = 0; bb < 4; ++bb)
                #pragma unroll
                for (int oo = 0; oo < 8; ++oo) {
                    acc[bb][oo].x += xr[bb].x * wr[oo].x - xr[bb].y * wr[oo].y;
                    acc[bb][oo].y += xr[bb].x * wr[oo].y + xr[bb].y * wr[oo].x;
                }
        }
    }
    for (int bb = 0; bb < 4; ++bb) {
        float2* yp = Y + ((size_t)(f0 + ff) * (NB * NH) + (b0 + bb) * NH + oh * 32 + oo0);
        #pragma unroll
        for (int oo = 0; oo < 8; ++oo) yp[oo] = acc[bb][oo];
    }
}

// ---------------------------------------------------------------------------
// conv1 + gelu(tanh approx): h[b,o,l] = gelu(cb[o] + sum_i cw[o,i]*s[b,i,l])
__global__ __launch_bounds__(256) void conv_gelu_k(
        const float* __restrict__ s, const float* __restrict__ cw,
        const float* __restrict__ cb, int layer, float* __restrict__ h) {
    int tid = blockIdx.x * 256 + threadIdx.x;
    int b = tid >> 12;
    int l = tid & (LEN - 1);
    float xr[NH];
    #pragma unroll
    for (int i = 0; i < NH; ++i) xr[i] = s[((size_t)b * NH + i) * LEN + l];
    const float* w  = cw + (size_t)layer * NH * NH;
    const float* bb = cb + layer * NH;
    for (int o = 0; o < NH; ++o) {
        float acc = bb[o];
        #pragma unroll
        for (int i = 0; i < NH; ++i) acc += w[o * NH + i] * xr[i];
        float c = 0.7978845608028654f * (acc + 0.044715f * acc * acc * acc);
        float g = 0.5f * acc * (1.0f + tanhf(c));
        h[((size_t)b * NH + o) * LEN + l] = g;
    }
}

// ---------------------------------------------------------------------------
// conv2 + residual: v[b,o,l] += cb[o] + sum_i cw[o,i]*h[b,i,l]
__global__ __launch_bounds__(256) void conv_res_k(
        const float* __restrict__ h, const float* __restrict__ cw,
        const float* __restrict__ cb, int layer, float* __restrict__ v) {
    int tid = blockIdx.x * 256 + threadIdx.x;
    int b = tid >> 12;
    int l = tid & (LEN - 1);
    float xr[NH];
    #pragma unroll
    for (int i = 0; i < NH; ++i) xr[i] = h[((size_t)b * NH + i) * LEN + l];
    const float* w  = cw + (size_t)layer * NH * NH;
    const float* bb = cb + layer * NH;
    for (int o = 0; o < NH; ++o) {
        float acc = bb[o];
        #pragma unroll
        for (int i = 0; i < NH; ++i) acc += w[o * NH + i] * xr[i];
        size_t idx = ((size_t)b * NH + o) * LEN + l;
        v[idx] = v[idx] + acc;
    }
}

// ---------------------------------------------------------------------------
// decoder: out[b,l] = db + sum_i dw[i]*v[b,i,l]
__global__ __launch_bounds__(256) void decoder_k(
        const float* __restrict__ v, const float* __restrict__ dw,
        const float* __restrict__ db, float* __restrict__ out) {
    int tid = blockIdx.x * 256 + threadIdx.x;
    int b = tid >> 12;
    int l = tid & (LEN - 1);
    float acc = db[0];
    for (int i = 0; i < NH; ++i) acc += dw[i] * v[((size_t)b * NH + i) * LEN + l];
    out[(size_t)b * LEN + l] = acc;
}

// ---------------------------------------------------------------------------
extern "C" void kernel_launch(void* const* d_in, const int* in_sizes, int n_in,
                              void* d_out, int out_size, void* d_ws, size_t ws_size,
                              hipStream_t stream) {
    const float* u_in   = (const float*)d_in[0];
    const float* x_in   = (const float*)d_in[1];
    const float* enc_w  = (const float*)d_in[2];
    const float* enc_b  = (const float*)d_in[3];
    const float* dec_w  = (const float*)d_in[4];
    const float* dec_b  = (const float*)d_in[5];
    const float* conv1w = (const float*)d_in[6];
    const float* conv1b = (const float*)d_in[7];
    const float* conv2w = (const float*)d_in[8];
    const float* conv2b = (const float*)d_in[9];
    const float* sw0    = (const float*)d_in[10];
    const float* sb0    = (const float*)d_in[11];
    const float* sw1    = (const float*)d_in[12];
    const float* sb1    = (const float*)d_in[13];
    const float* sw2    = (const float*)d_in[14];
    const float* sb2    = (const float*)d_in[15];

    // workspace carve-up
    const size_t CPLX = (size_t)2048 * 2048;          // elements per complex buffer
    const size_t REAL = (size_t)NB * NH * LEN;        // elements per real buffer
    char* base = (char*)d_ws;
    float2* tw   = (float2*)base;                                  // 16 KB
    float2* bufA = (float2*)(base + 16384);                        // 32 MB
    float2* bufB = bufA + CPLX;                                    // 32 MB
    float*  sbuf = (float*)(bufB + CPLX);                          // 32 MB
    float*  vbuf = sbuf + REAL;                                    // 32 MB
    size_t need = 16384 + 2 * CPLX * sizeof(float2) + 2 * REAL * sizeof(float);
    if (ws_size < need) return;  // insufficient scratch: leave d_out poisoned (visible failure)

    fill_tw<<<8, 256, 0, stream>>>(tw);
    encoder_k<<<(NB * LEN) / 256, 256, 0, stream>>>(x_in, u_in, enc_w, enc_b, vbuf);

    for (int l = 0; l < NLAYER; ++l) {
        fft_fwd_k  <<<NB * NH, 256, 0, stream>>>(vbuf, bufA, tw);
        transpose_k<<<dim3(64, 64), 256, 0, stream>>>(bufA, bufB);          // Xt -> X (f-major)
        specmm_k   <<<dim3(NF / 8, 2), 256, 0, stream>>>(bufB, bufA, sw0, sw1, sw2, l);
        transpose_k<<<dim3(64, 64), 256, 0, stream>>>(bufA, bufB);          // Y -> Yt (row-major)
        fft_inv_k  <<<NB * NH, 256, 0, stream>>>(bufB, sbuf, tw, sb0, sb1, sb2, l);
        conv_gelu_k<<<(NB * LEN) / 256, 256, 0, stream>>>(sbuf, conv1w, conv1b, l, (float*)bufA);
        conv_res_k <<<(NB * LEN) / 256, 256, 0, stream>>>((float*)bufA, conv2w, conv2b, l, vbuf);
    }
    decoder_k<<<(NB * LEN) / 256, 256, 0, stream>>>(vbuf, dec_w, dec_b, (float*)d_out);
}

// Round 3
// 1547.589 us; speedup vs baseline: 1.7603x; 1.1941x over previous
//
#include <hip/hip_runtime.h>
#include <math.h>

#ifndef M_PI
#define M_PI 3.14159265358979323846
#endif

#define LEN   4096
#define NB    32
#define NH    64
#define NF    2048   // modes stored (bins 0..2047)
#define NLAYER 4

// ---------------------------------------------------------------------------
// twiddle table: tw[k] = exp(-2*pi*i*k/4096), k = 0..2047
__global__ __launch_bounds__(256) void fill_tw(float2* __restrict__ tw) {
    int k = blockIdx.x * 256 + threadIdx.x;
    if (k < 2048) {
        double ang = -2.0 * M_PI * (double)k / 4096.0;
        tw[k] = make_float2((float)cos(ang), (float)sin(ang));
    }
}

// ---------------------------------------------------------------------------
// encoder
__global__ __launch_bounds__(256) void encoder_k(
        const float* __restrict__ x, const float* __restrict__ u,
        const float* __restrict__ ew, const float* __restrict__ eb,
        float* __restrict__ v) {
    int tid = blockIdx.x * 256 + threadIdx.x;
    int b = tid >> 12;
    int l = tid & (LEN - 1);
    float xv = x[(size_t)b * LEN + l];
    float u0 = u[((size_t)b * 3 + 0) * LEN + l];
    float u1 = u[((size_t)b * 3 + 1) * LEN + l];
    float u2 = u[((size_t)b * 3 + 2) * LEN + l];
    for (int h = 0; h < NH; ++h) {
        float a = eb[h] + ew[h*4+0]*xv + ew[h*4+1]*u0 + ew[h*4+2]*u1 + ew[h*4+3]*u2;
        v[((size_t)b * NH + h) * LEN + l] = a;
    }
}

// ---------------------------------------------------------------------------
// forward FFT, REAL-PAIR PACKED: block p handles rows 2p, 2p+1.
// z = v1 + i*v2; complex radix-2 DIT 4096; unpack:
//   X1[f] = 0.5*(Z[f] + conj(Z[-f])),  X2[f] = -0.5i*(Z[f] - conj(Z[-f]))
__global__ __launch_bounds__(256) void fft_fwd_k(
        const float* __restrict__ vin, float2* __restrict__ Xt,
        const float2* __restrict__ tw) {
    __shared__ float2 a[4096];
    int p = blockIdx.x;                          // 0..1023
    const float* s1 = vin + (size_t)(2*p)   * LEN;
    const float* s2 = vin + (size_t)(2*p+1) * LEN;
    int t = threadIdx.x;
    for (int j = 0; j < 16; ++j) {
        int idx = t + j * 256;
        int r = __brev((unsigned)idx) >> 20;
        a[r] = make_float2(s1[idx], s2[idx]);
    }
    __syncthreads();
    for (int s = 1; s <= 12; ++s) {
        int half = 1 << (s - 1);
        int tws  = 12 - s;
        for (int j = t; j < 2048; j += 256) {
            int k = j & (half - 1);
            int base = ((j >> (s - 1)) << s) + k;
            float2 w  = tw[k << tws];
            float2 x0 = a[base];
            float2 x1 = a[base + half];
            float tr = w.x * x1.x - w.y * x1.y;
            float ti = w.x * x1.y + w.y * x1.x;
            a[base]        = make_float2(x0.x + tr, x0.y + ti);
            a[base + half] = make_float2(x0.x - tr, x0.y - ti);
        }
        __syncthreads();
    }
    float2* d1 = Xt + (size_t)(2*p)   * NF;
    float2* d2 = Xt + (size_t)(2*p+1) * NF;
    for (int j = 0; j < 8; ++j) {
        int f = t + j * 256;                     // 0..2047
        float2 Zf = a[f];
        float2 Zm = a[(4096 - f) & 4095];
        d1[f] = make_float2(0.5f * (Zf.x + Zm.x), 0.5f * (Zf.y - Zm.y));
        d2[f] = make_float2(0.5f * (Zf.y + Zm.y), 0.5f * (Zm.x - Zf.x));
    }
}

// ---------------------------------------------------------------------------
// inverse FFT, REAL-PAIR PACKED: block p produces rows 2p, 2p+1.
// Z[f] = Y1[f] + i*Y2[f] (bin0: real parts only, per irfft semantics),
// Hermitian extension for f>2048, Nyquist=0. ifft; y1=Re, y2=Im.
__global__ __launch_bounds__(256) void fft_inv_k(
        const float2* __restrict__ Yt, float* __restrict__ sout,
        const float2* __restrict__ tw,
        const float* __restrict__ sb0, const float* __restrict__ sb1,
        const float* __restrict__ sb2, int layer) {
    __shared__ float2 a[4096];
    int p = blockIdx.x;                          // 0..1023
    int o = (2 * p) & (NH - 1);                  // even o
    const float2* s1 = Yt + (size_t)(2*p)   * NF;
    const float2* s2 = Yt + (size_t)(2*p+1) * NF;
    int t = threadIdx.x;
    for (int j = 0; j < 8; ++j) {
        int f = t + j * 256;                     // 0..2047
        float2 y1 = s1[f];
        float2 y2 = s2[f];
        float2 z;
        if (f == 0) z = make_float2(y1.x, y2.x);
        else        z = make_float2(y1.x - y2.y, y1.y + y2.x);
        a[__brev((unsigned)f) >> 20] = z;
    }
    for (int j = 0; j < 8; ++j) {
        int f = 2048 + t + j * 256;              // 2048..4095
        float2 z;
        if (f == 2048) {
            z = make_float2(0.0f, 0.0f);
        } else {
            int m = 4096 - f;                    // 1..2047
            float2 y1 = s1[m];
            float2 y2 = s2[m];
            z = make_float2(y1.x + y2.y, y2.x - y1.y);  // conj(Y1)+i*conj(Y2)
        }
        a[__brev((unsigned)f) >> 20] = z;
    }
    __syncthreads();
    for (int s = 1; s <= 12; ++s) {
        int half = 1 << (s - 1);
        int tws  = 12 - s;
        for (int j = t; j < 2048; j += 256) {
            int k = j & (half - 1);
            int base = ((j >> (s - 1)) << s) + k;
            float2 w = tw[k << tws];
            w.y = -w.y;                          // conjugate: inverse
            float2 x0 = a[base];
            float2 x1 = a[base + half];
            float tr = w.x * x1.x - w.y * x1.y;
            float ti = w.x * x1.y + w.y * x1.x;
            a[base]        = make_float2(x0.x + tr, x0.y + ti);
            a[base + half] = make_float2(x0.x - tr, x0.y - ti);
        }
        __syncthreads();
    }
    float bias1 = sb0[layer*NH+o]   + sb1[layer*NH+o]   + sb2[layer*NH+o];
    float bias2 = sb0[layer*NH+o+1] + sb1[layer*NH+o+1] + sb2[layer*NH+o+1];
    float* d1 = sout + (size_t)(2*p)   * LEN;
    float* d2 = sout + (size_t)(2*p+1) * LEN;
    const float sc = 1.0f / 4096.0f;
    for (int j = 0; j < 16; ++j) {
        int l = t + j * 256;
        float2 zz = a[l];
        d1[l] = zz.x * sc + bias1;
        d2[l] = zz.y * sc + bias2;
    }
}

// ---------------------------------------------------------------------------
// 2048x2048 complex transpose, 32x32 tiles
__global__ __launch_bounds__(256) void transpose_k(
        const float2* __restrict__ src, float2* __restrict__ dst) {
    __shared__ float2 tile[32][33];
    int tx = threadIdx.x & 31;
    int ty = threadIdx.x >> 5;
    int col = blockIdx.x * 32 + tx;
    for (int j = 0; j < 32; j += 8) {
        int row = blockIdx.y * 32 + ty + j;
        tile[ty + j][tx] = src[(size_t)row * 2048 + col];
    }
    __syncthreads();
    int ocol = blockIdx.y * 32 + tx;
    for (int j = 0; j < 32; j += 8) {
        int orow = blockIdx.x * 32 + ty + j;
        dst[(size_t)orow * 2048 + ocol] = tile[tx][ty + j];
    }
}

// ---------------------------------------------------------------------------
// spectral matmul, branch-summed weights + register-prefetch pipeline.
//   Weff[i,o,f] = w2[f] + [f<1024]*w1[f] + [f<512]*w0[f]
//   Y[f,b,o] = sum_i X[f,b,i] * Weff[i,o,f]
__global__ __launch_bounds__(256) void specmm_k(
        const float2* __restrict__ X, float2* __restrict__ Y,
        const float* __restrict__ w0, const float* __restrict__ w1,
        const float* __restrict__ w2, int layer) {
    __shared__ float2 Xs[8][32][9];   // [i][b][f] (+1 pad)
    __shared__ float2 Ws[8][32][9];   // [i][o][f] (+1 pad)
    int f0 = blockIdx.x * 8;
    int oh = blockIdx.y;
    int t  = threadIdx.x;
    int ff = t & 7;
    int u  = t >> 3;
    int b0  = (u & 7) * 4;
    int oo0 = (u >> 3) * 8;
    float2 acc[4][8];
    for (int bb = 0; bb < 4; ++bb)
        for (int oo = 0; oo < 8; ++oo)
            acc[bb][oo] = make_float2(0.0f, 0.0f);

    const float2* w0b = (const float2*)w0 + (size_t)layer * NH * NH * 512;
    const float2* w1b = (const float2*)w1 + (size_t)layer * NH * NH * 1024;
    const float2* w2b = (const float2*)w2 + (size_t)layer * NH * NH * 2048;
    const bool has0 = (f0 < 512);
    const bool has1 = (f0 < 1024);

    const int bq = t & 31, fq = t >> 5;          // X staging role
    const int oq = t & 31, iq = t >> 5;          // W staging role

    float2 xv[8], wv[8];
    #define LOAD_CHUNK(ic_)                                                     \
    {                                                                           \
        const float2* gx = X + ((size_t)(f0 + fq) * (NB * NH) + bq * NH + (ic_) * 8); \
        _Pragma("unroll")                                                       \
        for (int ii = 0; ii < 8; ++ii) xv[ii] = gx[ii];                         \
        const size_t io = (size_t)((ic_) * 8 + iq) * NH + (oh * 32 + oq);       \
        const float2* g2 = w2b + io * 2048 + f0;                                \
        _Pragma("unroll")                                                       \
        for (int ii = 0; ii < 8; ++ii) wv[ii] = g2[ii];                         \
        if (has1) {                                                             \
            const float2* g1 = w1b + io * 1024 + f0;                            \
            _Pragma("unroll")                                                   \
            for (int ii = 0; ii < 8; ++ii) { float2 q = g1[ii]; wv[ii].x += q.x; wv[ii].y += q.y; } \
        }                                                                       \
        if (has0) {                                                             \
            const float2* g0 = w0b + io * 512 + f0;                             \
            _Pragma("unroll")                                                   \
            for (int ii = 0; ii < 8; ++ii) { float2 q = g0[ii]; wv[ii].x += q.x; wv[ii].y += q.y; } \
        }                                                                       \
    }

    LOAD_CHUNK(0);
    for (int ic = 0; ic < 8; ++ic) {
        __syncthreads();                          // previous compute done
        #pragma unroll
        for (int ii = 0; ii < 8; ++ii) Xs[ii][bq][fq] = xv[ii];
        #pragma unroll
        for (int ii = 0; ii < 8; ++ii) Ws[iq][oq][ii] = wv[ii];
        __syncthreads();
        if (ic < 7) LOAD_CHUNK(ic + 1);           // prefetch next; hidden by compute
        #pragma unroll
        for (int ii = 0; ii < 8; ++ii) {
            float2 xr[4], wr[8];
            #pragma unroll
            for (int bb = 0; bb < 4; ++bb) xr[bb] = Xs[ii][b0 + bb][ff];
            #pragma unroll
            for (int oo = 0; oo < 8; ++oo) wr[oo] = Ws[ii][oo0 + oo][ff];
            #pragma unroll
            for (int bb = 0; bb < 4; ++bb)
                #pragma unroll
                for (int oo = 0; oo < 8; ++oo) {
                    acc[bb][oo].x += xr[bb].x * wr[oo].x - xr[bb].y * wr[oo].y;
                    acc[bb][oo].y += xr[bb].x * wr[oo].y + xr[bb].y * wr[oo].x;
                }
        }
    }
    #undef LOAD_CHUNK
    for (int bb = 0; bb < 4; ++bb) {
        float2* yp = Y + ((size_t)(f0 + ff) * (NB * NH) + (b0 + bb) * NH + oh * 32 + oo0);
        #pragma unroll
        for (int oo = 0; oo < 8; ++oo) yp[oo] = acc[bb][oo];
    }
}

// ---------------------------------------------------------------------------
// fused conv1+gelu+conv2+residual: per (b,l), h stays in registers.
// i-outer structure: compute h_i, immediately scatter into acc2[o].
__global__ __launch_bounds__(256) void conv_fused_k(
        const float* __restrict__ s,
        const float* __restrict__ c1w, const float* __restrict__ c1b,
        const float* __restrict__ c2w, const float* __restrict__ c2b,
        int layer, float* __restrict__ v) {
    int tid = blockIdx.x * 256 + threadIdx.x;
    int b = tid >> 12;
    int l = tid & (LEN - 1);
    float xr[NH];
    #pragma unroll
    for (int i = 0; i < NH; ++i) xr[i] = s[((size_t)b * NH + i) * LEN + l];
    const float* w1 = c1w + (size_t)layer * NH * NH;
    const float* b1 = c1b + layer * NH;
    const float* w2 = c2w + (size_t)layer * NH * NH;
    const float* b2 = c2b + layer * NH;
    float acc2[NH];
    #pragma unroll
    for (int o = 0; o < NH; ++o) acc2[o] = b2[o];
    for (int i = 0; i < NH; ++i) {               // not unrolled: keeps I-size sane
        float acc = b1[i];
        #pragma unroll
        for (int k = 0; k < NH; ++k) acc += w1[i * NH + k] * xr[k];
        float cc = 0.7978845608028654f * (acc + 0.044715f * acc * acc * acc);
        float e  = __expf(2.0f * cc);
        float th = 1.0f - 2.0f / (e + 1.0f);
        float h  = 0.5f * acc * (1.0f + th);
        #pragma unroll
        for (int o = 0; o < NH; ++o) acc2[o] += w2[o * NH + i] * h;
    }
    #pragma unroll
    for (int o = 0; o < NH; ++o) {
        size_t idx = ((size_t)b * NH + o) * LEN + l;
        v[idx] = v[idx] + acc2[o];
    }
}

// ---------------------------------------------------------------------------
// decoder
__global__ __launch_bounds__(256) void decoder_k(
        const float* __restrict__ v, const float* __restrict__ dw,
        const float* __restrict__ db, float* __restrict__ out) {
    int tid = blockIdx.x * 256 + threadIdx.x;
    int b = tid >> 12;
    int l = tid & (LEN - 1);
    float acc = db[0];
    for (int i = 0; i < NH; ++i) acc += dw[i] * v[((size_t)b * NH + i) * LEN + l];
    out[(size_t)b * LEN + l] = acc;
}

// ---------------------------------------------------------------------------
extern "C" void kernel_launch(void* const* d_in, const int* in_sizes, int n_in,
                              void* d_out, int out_size, void* d_ws, size_t ws_size,
                              hipStream_t stream) {
    const float* u_in   = (const float*)d_in[0];
    const float* x_in   = (const float*)d_in[1];
    const float* enc_w  = (const float*)d_in[2];
    const float* enc_b  = (const float*)d_in[3];
    const float* dec_w  = (const float*)d_in[4];
    const float* dec_b  = (const float*)d_in[5];
    const float* conv1w = (const float*)d_in[6];
    const float* conv1b = (const float*)d_in[7];
    const float* conv2w = (const float*)d_in[8];
    const float* conv2b = (const float*)d_in[9];
    const float* sw0    = (const float*)d_in[10];
    const float* sb0    = (const float*)d_in[11];
    const float* sw1    = (const float*)d_in[12];
    const float* sb1    = (const float*)d_in[13];
    const float* sw2    = (const float*)d_in[14];
    const float* sb2    = (const float*)d_in[15];

    const size_t CPLX = (size_t)2048 * 2048;
    const size_t REAL = (size_t)NB * NH * LEN;
    char* base = (char*)d_ws;
    float2* tw   = (float2*)base;
    float2* bufA = (float2*)(base + 16384);
    float2* bufB = bufA + CPLX;
    float*  sbuf = (float*)(bufB + CPLX);
    float*  vbuf = sbuf + REAL;
    size_t need = 16384 + 2 * CPLX * sizeof(float2) + 2 * REAL * sizeof(float);
    if (ws_size < need) return;

    fill_tw<<<8, 256, 0, stream>>>(tw);
    encoder_k<<<(NB * LEN) / 256, 256, 0, stream>>>(x_in, u_in, enc_w, enc_b, vbuf);

    for (int l = 0; l < NLAYER; ++l) {
        fft_fwd_k  <<<NB * NH / 2, 256, 0, stream>>>(vbuf, bufA, tw);
        transpose_k<<<dim3(64, 64), 256, 0, stream>>>(bufA, bufB);          // Xt -> X
        specmm_k   <<<dim3(NF / 8, 2), 256, 0, stream>>>(bufB, bufA, sw0, sw1, sw2, l);
        transpose_k<<<dim3(64, 64), 256, 0, stream>>>(bufA, bufB);          // Y -> Yt
        fft_inv_k  <<<NB * NH / 2, 256, 0, stream>>>(bufB, sbuf, tw, sb0, sb1, sb2, l);
        conv_fused_k<<<(NB * LEN) / 256, 256, 0, stream>>>(sbuf, conv1w, conv1b,
                                                           conv2w, conv2b, l, vbuf);
    }
    decoder_k<<<(NB * LEN) / 256, 256, 0, stream>>>(vbuf, dec_w, dec_b, (float*)d_out);
}